// Round 8
// baseline (345.402 us; speedup 1.0000x reference)
//
#include <hip/hip_runtime.h>
#include <stdint.h>

typedef __attribute__((ext_vector_type(4))) float floatx4;
typedef __attribute__((ext_vector_type(8))) short shortx8;

#define LN_EPS 1e-5f

__device__ __forceinline__ unsigned short f2b(float f) {
  unsigned u = __builtin_bit_cast(unsigned, f);
  u = (u + 0x7FFFu + ((u >> 16) & 1u)) >> 16;
  return (unsigned short)u;
}
__device__ __forceinline__ float b2f(unsigned short h) {
  return __builtin_bit_cast(float, (unsigned)h << 16);
}
__device__ __forceinline__ float sigm(float x) { return 1.0f / (1.0f + expf(-x)); }

// async global->LDS 16B: lds dest is wave-uniform base; lane i lands at base + i*16
__device__ __forceinline__ void g2l16(const unsigned short* g, unsigned short* l) {
  __builtin_amdgcn_global_load_lds(
      (const __attribute__((address_space(1))) unsigned int*)g,
      (__attribute__((address_space(3))) unsigned int*)l, 16, 0, 0);
}

// ---------------- block reduction helpers (256 threads = 4 waves) -----------
__device__ __forceinline__ float wave_sum(float v) {
#pragma unroll
  for (int o = 32; o; o >>= 1) v += __shfl_down(v, o, 64);
  return v;
}
__device__ __forceinline__ float block_sum(float v, float* s) {
  v = wave_sum(v);
  __syncthreads();
  if ((threadIdx.x & 63) == 0) s[threadIdx.x >> 6] = v;
  __syncthreads();
  return s[0] + s[1] + s[2] + s[3];
}

// ---------------- merged: pw GEMM (blocks 0..191) + transposes + zeroing ----
// pw = prev(f32) @ Wp(f32)^T -> pwb bf16 (reg-cvt staging both operands).
// blocks [192, 7104): 32x32 transpose tiles. block 192 zeroes rowsum; block
// 193 zeroes rstat.
__global__ __launch_bounds__(256) void k_prep_pw(
    const float* __restrict__ prev, const float* __restrict__ wp,
    const float* __restrict__ Wu, const float* __restrict__ Wr,
    const float* __restrict__ Wn,
    unsigned short* __restrict__ Wtur, unsigned short* __restrict__ Wtn,
    unsigned short* __restrict__ Wtp, unsigned short* __restrict__ pwb,
    float* __restrict__ rs, float* __restrict__ rstat) {
  __shared__ unsigned short As[2][64 * 64];
  __shared__ unsigned short Bs[2][64 * 64];
  const int bid = blockIdx.x;
  const int tid = threadIdx.x;
  if (bid < 192) {
    const int wave = tid >> 6, lane = tid & 63;
    const int swz = (bid & 7) * 24 + (bid >> 3);  // XCD-bijective over 192
    const int m0 = (swz % 16) * 64;
    const int n0 = (swz / 16) * 64;
    const int wm = wave & 1, wn = wave >> 1;
    const int l16 = lane & 15, quad = lane >> 4;
    const int srow8 = lane >> 3;
    const int c8 = ((lane & 7) ^ srow8) * 8;

    const float* gAf[2];
    const float* gBf[2];
    int lOff[2];
#pragma unroll
    for (int j = 0; j < 2; j++) {
      const int rb = wave * 16 + j * 8;
      gAf[j] = prev + (long)(m0 + rb + srow8) * 1024 + c8;
      gBf[j] = wp + (long)(n0 + rb + srow8) * 1024 + c8;
      lOff[j] = rb * 64;
    }
    int offA[2][2], offB[2][2];
#pragma unroll
    for (int ks = 0; ks < 2; ks++)
#pragma unroll
      for (int i = 0; i < 2; i++) {
        int r = wm * 32 + i * 16 + l16;
        offA[ks][i] = r * 64 + (((ks * 4 + quad) ^ (r & 7)) * 8);
        r = wn * 32 + i * 16 + l16;
        offB[ks][i] = r * 64 + (((ks * 4 + quad) ^ (r & 7)) * 8);
      }

    floatx4 acc[2][2] = {};

#pragma unroll
    for (int j = 0; j < 2; j++) {
      floatx4 a0 = *(const floatx4*)(gAf[j]);
      floatx4 a1 = *(const floatx4*)(gAf[j] + 4);
      floatx4 b0 = *(const floatx4*)(gBf[j]);
      floatx4 b1 = *(const floatx4*)(gBf[j] + 4);
      unsigned short ta[8], tb[8];
#pragma unroll
      for (int i = 0; i < 4; i++) {
        ta[i] = f2b(a0[i]); ta[4 + i] = f2b(a1[i]);
        tb[i] = f2b(b0[i]); tb[4 + i] = f2b(b1[i]);
      }
      *(uint4*)&As[0][lOff[j] + lane * 8] = *(uint4*)ta;
      *(uint4*)&Bs[0][lOff[j] + lane * 8] = *(uint4*)tb;
    }
    __syncthreads();

    const int nt = 16;
    for (int t = 0; t < nt; t++) {
      const int cur = t & 1;
      floatx4 a0[2], a1[2], b0[2], b1[2];
      if (t + 1 < nt) {
        const int kn = (t + 1) << 6;
#pragma unroll
        for (int j = 0; j < 2; j++) {
          a0[j] = *(const floatx4*)(gAf[j] + kn);
          a1[j] = *(const floatx4*)(gAf[j] + kn + 4);
          b0[j] = *(const floatx4*)(gBf[j] + kn);
          b1[j] = *(const floatx4*)(gBf[j] + kn + 4);
        }
      }
#pragma unroll
      for (int ks = 0; ks < 2; ks++) {
        shortx8 af[2], bf[2];
#pragma unroll
        for (int i = 0; i < 2; i++) af[i] = *(const shortx8*)&As[cur][offA[ks][i]];
#pragma unroll
        for (int j = 0; j < 2; j++) bf[j] = *(const shortx8*)&Bs[cur][offB[ks][j]];
#pragma unroll
        for (int i = 0; i < 2; i++)
#pragma unroll
          for (int j = 0; j < 2; j++)
            acc[i][j] = __builtin_amdgcn_mfma_f32_16x16x32_bf16(af[i], bf[j], acc[i][j], 0, 0, 0);
      }
      if (t + 1 < nt) {
#pragma unroll
        for (int j = 0; j < 2; j++) {
          unsigned short ta[8], tb[8];
#pragma unroll
          for (int i = 0; i < 4; i++) {
            ta[i] = f2b(a0[j][i]); ta[4 + i] = f2b(a1[j][i]);
            tb[i] = f2b(b0[j][i]); tb[4 + i] = f2b(b1[j][i]);
          }
          *(uint4*)&As[cur ^ 1][lOff[j] + lane * 8] = *(uint4*)ta;
          *(uint4*)&Bs[cur ^ 1][lOff[j] + lane * 8] = *(uint4*)tb;
        }
      }
      __syncthreads();
    }

#pragma unroll
    for (int i = 0; i < 2; i++)
#pragma unroll
      for (int j = 0; j < 2; j++) {
        const int rbase = m0 + wm * 32 + i * 16 + quad * 4;
        const int c = n0 + wn * 32 + j * 16 + l16;
#pragma unroll
        for (int r = 0; r < 4; r++)
          pwb[(long)(rbase + r) * 768 + c] = f2b(acc[i][j][r]);
      }
    return;
  }
  // ---- transpose part (aliases LDS)
  float(*tile)[33] = (float(*)[33]) & As[0][0];
  if (bid == 192) {
    floatx4 z = {0.f, 0.f, 0.f, 0.f};
    *(floatx4*)(rs + tid * 4) = z;
  }
  if (bid == 193) {
    floatx4 z = {0.f, 0.f, 0.f, 0.f};
    *(floatx4*)(rstat + tid * 8) = z;
    *(floatx4*)(rstat + tid * 8 + 4) = z;
  }
  int t = bid - 192;
  const float* in;
  unsigned short* out;
  int K, kx, ny;
  if (t < 6144) {
    const int which = t >> 11;
    const int t2 = t & 2047;
    kx = t2 & 63;
    ny = t2 >> 6;
    K = 2048;
    in = which == 0 ? Wu : (which == 1 ? Wr : Wn);
    out = which == 0 ? Wtur : (which == 1 ? Wtur + 1024 * 2048 : Wtn);
  } else {
    const int t2 = t - 6144;
    kx = t2 % 24;
    ny = t2 / 24;
    K = 768;
    in = wp;
    out = Wtp;
  }
  const int N = 1024;
  const int k0 = kx * 32, n0 = ny * 32;
  const int tx = tid & 31, ty = tid >> 5;
#pragma unroll
  for (int i = 0; i < 32; i += 8)
    tile[ty + i][tx] = in[(long)(k0 + ty + i) * N + n0 + tx];
  __syncthreads();
#pragma unroll
  for (int i = 0; i < 32; i += 8)
    out[(long)(n0 + ty + i) * K + k0 + tx] = f2b(tile[tx][ty + i]);
}

// ---------------- scores: A=pwb bf16 (g2l16), B=tokens f32 (reg-cvt) --------
__global__ __launch_bounds__(256) void k_scores(
    const unsigned short* __restrict__ A, long sAb, int lda,
    const float* __restrict__ toksf,
    int K, float scale,
    unsigned short* __restrict__ out2, int ldc, long sCb,
    float* __restrict__ rs) {
  __shared__ unsigned short As[2][64 * 64];
  __shared__ unsigned short Bs[2][64 * 64];
  const int tid = threadIdx.x;
  const int wave = tid >> 6, lane = tid & 63;
  const int b = blockIdx.z;
  const int m0 = 0, n0 = blockIdx.y * 64;
  const int wm = wave & 1, wn = wave >> 1;
  const int l16 = lane & 15, quad = lane >> 4;
  const int srow8 = lane >> 3;
  const int c8 = ((lane & 7) ^ srow8) * 8;
  const unsigned short* Ab = A + (long)b * sAb;

  const unsigned short* gA[2];
  const float* gBf[2];
  int lOff[2];
#pragma unroll
  for (int j = 0; j < 2; j++) {
    const int rb = wave * 16 + j * 8;
    gA[j] = Ab + (long)(m0 + rb + srow8) * lda + c8;
    gBf[j] = toksf + (long)b * 1572864 + (long)(n0 + rb + srow8) * 768 + c8;
    lOff[j] = rb * 64;
  }
  int offA[2][2], offB[2][2];
#pragma unroll
  for (int ks = 0; ks < 2; ks++)
#pragma unroll
    for (int i = 0; i < 2; i++) {
      int r = wm * 32 + i * 16 + l16;
      offA[ks][i] = r * 64 + (((ks * 4 + quad) ^ (r & 7)) * 8);
      r = wn * 32 + i * 16 + l16;
      offB[ks][i] = r * 64 + (((ks * 4 + quad) ^ (r & 7)) * 8);
    }

  floatx4 acc[2][2] = {};

#pragma unroll
  for (int j = 0; j < 2; j++) {
    g2l16(gA[j], &As[0][lOff[j]]);
    floatx4 v0 = *(const floatx4*)(gBf[j]);
    floatx4 v1 = *(const floatx4*)(gBf[j] + 4);
    unsigned short t8[8];
#pragma unroll
    for (int i = 0; i < 4; i++) { t8[i] = f2b(v0[i]); t8[4 + i] = f2b(v1[i]); }
    *(uint4*)&Bs[0][lOff[j] + lane * 8] = *(uint4*)t8;
  }
  __syncthreads();

  const int nt = K >> 6;
  for (int t = 0; t < nt; t++) {
    const int cur = t & 1;
    floatx4 w0[2], w1[2];
    if (t + 1 < nt) {
      const int kn = (t + 1) << 6;
#pragma unroll
      for (int j = 0; j < 2; j++) {
        g2l16(gA[j] + kn, &As[cur ^ 1][lOff[j]]);
        w0[j] = *(const floatx4*)(gBf[j] + kn);
        w1[j] = *(const floatx4*)(gBf[j] + kn + 4);
      }
    }
#pragma unroll
    for (int ks = 0; ks < 2; ks++) {
      shortx8 af[2], bf[2];
#pragma unroll
      for (int i = 0; i < 2; i++) af[i] = *(const shortx8*)&As[cur][offA[ks][i]];
#pragma unroll
      for (int j = 0; j < 2; j++) bf[j] = *(const shortx8*)&Bs[cur][offB[ks][j]];
#pragma unroll
      for (int i = 0; i < 2; i++)
#pragma unroll
        for (int j = 0; j < 2; j++)
          acc[i][j] = __builtin_amdgcn_mfma_f32_16x16x32_bf16(af[i], bf[j], acc[i][j], 0, 0, 0);
    }
    if (t + 1 < nt) {
#pragma unroll
      for (int j = 0; j < 2; j++) {
        unsigned short t8[8];
#pragma unroll
        for (int i = 0; i < 4; i++) { t8[i] = f2b(w0[j][i]); t8[4 + i] = f2b(w1[j][i]); }
        *(uint4*)&Bs[cur ^ 1][lOff[j] + lane * 8] = *(uint4*)t8;
      }
    }
    __syncthreads();
  }

#pragma unroll
  for (int i = 0; i < 2; i++) {
    float psum[4] = {0.f, 0.f, 0.f, 0.f};
#pragma unroll
    for (int j = 0; j < 2; j++) {
      const int rbase = m0 + wm * 32 + i * 16 + quad * 4;
      const int c = n0 + wn * 32 + j * 16 + l16;
#pragma unroll
      for (int r = 0; r < 4; r++) {
        const float e = expf(acc[i][j][r] * scale);
        out2[(long)b * sCb + (long)(rbase + r) * ldc + c] = f2b(e);
        psum[r] += e;
      }
    }
#pragma unroll
    for (int r = 0; r < 4; r++) {
      float s = psum[r];
      s += __shfl_xor(s, 1, 64);
      s += __shfl_xor(s, 2, 64);
      s += __shfl_xor(s, 4, 64);
      s += __shfl_xor(s, 8, 64);
      if (l16 == 0)
        atomicAdd(rs + (long)b * 64 + m0 + wm * 32 + i * 16 + quad * 4 + r, s);
    }
  }
}

// ---------------- rw = attnb(exp) @ tokens(f32) via MFMA, K-split x2 --------
__global__ __launch_bounds__(256) void k_routed_mfma(
    const unsigned short* __restrict__ attnb,
    const float* __restrict__ tokf,
    float* __restrict__ parts) {
  __shared__ unsigned short As[64 * 40];
  __shared__ unsigned short Bs[32 * 66];
  const int kc = blockIdx.x, nt = blockIdx.y, b = blockIdx.z;
  const int tid = threadIdx.x;
  const int wave = tid >> 6, lane = tid & 63;
  const int wm = wave & 1, wn = wave >> 1;
  const int l16 = lane & 15, quad = lane >> 4;
  const int n0 = nt * 64;
  const long abase = (long)b * 131072 + (long)kc * 1024;
  const long tbase = ((long)b * 2048 + (long)kc * 1024) * 768;
  const int srow = tid >> 2, skc = (tid & 3) * 8;
  const int bk = tid >> 3, bd = (tid & 7) * 8;

  floatx4 acc[2][2] = {};

  uint4 pa = *(const uint4*)(attnb + abase + (long)srow * 2048 + skc);
  floatx4 f0 = *(const floatx4*)(tokf + tbase + (long)bk * 768 + n0 + bd);
  floatx4 f1 = *(const floatx4*)(tokf + tbase + (long)bk * 768 + n0 + bd + 4);

  for (int k0 = 0; k0 < 1024; k0 += 32) {
    *(uint4*)&As[srow * 40 + skc] = pa;
    {
      unsigned short t8[8];
#pragma unroll
      for (int i = 0; i < 4; i++) { t8[i] = f2b(f0[i]); t8[4 + i] = f2b(f1[i]); }
      unsigned short* dst = &Bs[bk * 66 + bd];
#pragma unroll
      for (int w2 = 0; w2 < 4; w2++) *(unsigned*)(dst + w2 * 2) = ((unsigned*)t8)[w2];
    }
    if (k0 + 32 < 1024) {
      pa = *(const uint4*)(attnb + abase + (long)srow * 2048 + (k0 + 32) + skc);
      f0 = *(const floatx4*)(tokf + tbase + (long)(k0 + 32 + bk) * 768 + n0 + bd);
      f1 = *(const floatx4*)(tokf + tbase + (long)(k0 + 32 + bk) * 768 + n0 + bd + 4);
    }
    asm volatile("s_waitcnt lgkmcnt(0)" ::: "memory");
    __builtin_amdgcn_s_barrier();
    __builtin_amdgcn_sched_barrier(0);

    shortx8 a0 = *(const shortx8*)&As[(wm * 32 + 0  + l16) * 40 + quad * 8];
    shortx8 a1 = *(const shortx8*)&As[(wm * 32 + 16 + l16) * 40 + quad * 8];
    shortx8 b0, b1;
#pragma unroll
    for (int j = 0; j < 8; j++) {
      b0[j] = *(const short*)&Bs[(quad * 8 + j) * 66 + wn * 32 + l16];
      b1[j] = *(const short*)&Bs[(quad * 8 + j) * 66 + wn * 32 + 16 + l16];
    }
    acc[0][0] = __builtin_amdgcn_mfma_f32_16x16x32_bf16(a0, b0, acc[0][0], 0, 0, 0);
    acc[0][1] = __builtin_amdgcn_mfma_f32_16x16x32_bf16(a0, b1, acc[0][1], 0, 0, 0);
    acc[1][0] = __builtin_amdgcn_mfma_f32_16x16x32_bf16(a1, b0, acc[1][0], 0, 0, 0);
    acc[1][1] = __builtin_amdgcn_mfma_f32_16x16x32_bf16(a1, b1, acc[1][1], 0, 0, 0);
    __builtin_amdgcn_s_barrier();
  }

#pragma unroll
  for (int im = 0; im < 2; im++)
#pragma unroll
    for (int in_ = 0; in_ < 2; in_++) {
      const int rbase = wm * 32 + im * 16 + quad * 4;
      const int c = n0 + wn * 32 + in_ * 16 + l16;
#pragma unroll
      for (int r = 0; r < 4; r++)
        parts[(long)kc * 786432 + ((long)b * 64 + rbase + r) * 768 + c] =
            acc[im][in_][r];
    }
}

// ---------------- proj2 (blocks 0..255, + row-stat atomics) + prev-LN ------
// proj2: routed[row][c] = (parts0+parts1)[row][:].Wtp[c][:] + rowsum[row]*bp[c]
//        and atomicAdd per-row (sum v, sum v^2) into rstat[row*2 +{0,1}]
// prevLN (blocks 256..1279): psn[r][:] = LN(prev[r])*g_st + be_st  (bf16)
__global__ __launch_bounds__(256) void k_proj2_ln(
    const float* __restrict__ P0, int lda,
    const unsigned short* __restrict__ Bt, int ldb,
    int K,
    const float* __restrict__ bp, const float* __restrict__ rowsum,
    float* __restrict__ out, int ldc, float* __restrict__ rstat,
    const float* __restrict__ prev,
    const float* __restrict__ g_st, const float* __restrict__ be_st,
    unsigned short* __restrict__ psn) {
  __shared__ unsigned short As[2][64 * 64];
  __shared__ unsigned short Bs[2][64 * 64];
  const int tid = threadIdx.x;
  if (blockIdx.x >= 256) {
    float* scr = (float*)&As[0][0];
    const long r = blockIdx.x - 256;
    floatx4 v = *(const floatx4*)(prev + r * 1024 + tid * 4);
    float s1 = v[0] + v[1] + v[2] + v[3];
    float s2 = v[0] * v[0] + v[1] * v[1] + v[2] * v[2] + v[3] * v[3];
    s1 = block_sum(s1, scr);
    s2 = block_sum(s2, scr);
    const float mean = s1 * (1.0f / 1024.0f);
    const float var = s2 * (1.0f / 1024.0f) - mean * mean;
    const float rstd = rsqrtf(var + LN_EPS);
    unsigned short t4[4];
#pragma unroll
    for (int i = 0; i < 4; i++) {
      const int d = tid * 4 + i;
      t4[i] = f2b((v[i] - mean) * rstd * g_st[d] + be_st[d]);
    }
    *(uint2*)(psn + r * 1024 + tid * 4) = *(uint2*)t4;
    return;
  }
  const int wave = tid >> 6, lane = tid & 63;
  const int flat = blockIdx.x;
  const int swz = (flat & 7) * 32 + (flat >> 3);  // bijective over 256
  const int m0 = (swz % 16) * 64;
  const int n0 = (swz / 16) * 64;
  const int wm = wave & 1, wn = wave >> 1;
  const int l16 = lane & 15, quad = lane >> 4;
  const int srow8 = lane >> 3;
  const int c8 = ((lane & 7) ^ srow8) * 8;

  const float* gAf[2];
  const unsigned short* gB[2];
  int lOff[2];
#pragma unroll
  for (int j = 0; j < 2; j++) {
    const int rb = wave * 16 + j * 8;
    gAf[j] = P0 + (long)(m0 + rb + srow8) * lda + c8;
    gB[j] = Bt + (long)(n0 + rb + srow8) * ldb + c8;
    lOff[j] = rb * 64;
  }
  int offA[2][2], offB[2][2];
#pragma unroll
  for (int ks = 0; ks < 2; ks++)
#pragma unroll
    for (int i = 0; i < 2; i++) {
      int r = wm * 32 + i * 16 + l16;
      offA[ks][i] = r * 64 + (((ks * 4 + quad) ^ (r & 7)) * 8);
      r = wn * 32 + i * 16 + l16;
      offB[ks][i] = r * 64 + (((ks * 4 + quad) ^ (r & 7)) * 8);
    }

  floatx4 acc[2][2] = {};

#pragma unroll
  for (int j = 0; j < 2; j++) {
    g2l16(gB[j], &Bs[0][lOff[j]]);
    floatx4 a0 = *(const floatx4*)(gAf[j]);
    floatx4 a1 = *(const floatx4*)(gAf[j] + 4);
    floatx4 b0 = *(const floatx4*)(gAf[j] + 786432);
    floatx4 b1 = *(const floatx4*)(gAf[j] + 786432 + 4);
    unsigned short t8[8];
#pragma unroll
    for (int i = 0; i < 4; i++) { t8[i] = f2b(a0[i] + b0[i]); t8[4 + i] = f2b(a1[i] + b1[i]); }
    *(uint4*)&As[0][lOff[j] + lane * 8] = *(uint4*)t8;
  }
  __syncthreads();

  const int nt = K >> 6;
  for (int t = 0; t < nt; t++) {
    const int cur = t & 1;
    floatx4 a0[2], a1[2], p0[2], p1[2];
    if (t + 1 < nt) {
      const int kn = (t + 1) << 6;
#pragma unroll
      for (int j = 0; j < 2; j++) {
        g2l16(gB[j] + kn, &Bs[cur ^ 1][lOff[j]]);
        a0[j] = *(const floatx4*)(gAf[j] + kn);
        a1[j] = *(const floatx4*)(gAf[j] + kn + 4);
        p0[j] = *(const floatx4*)(gAf[j] + kn + 786432);
        p1[j] = *(const floatx4*)(gAf[j] + kn + 786432 + 4);
      }
    }
#pragma unroll
    for (int ks = 0; ks < 2; ks++) {
      shortx8 af[2], bf[2];
#pragma unroll
      for (int i = 0; i < 2; i++) af[i] = *(const shortx8*)&As[cur][offA[ks][i]];
#pragma unroll
      for (int j = 0; j < 2; j++) bf[j] = *(const shortx8*)&Bs[cur][offB[ks][j]];
#pragma unroll
      for (int i = 0; i < 2; i++)
#pragma unroll
        for (int j = 0; j < 2; j++)
          acc[i][j] = __builtin_amdgcn_mfma_f32_16x16x32_bf16(af[i], bf[j], acc[i][j], 0, 0, 0);
    }
    if (t + 1 < nt) {
#pragma unroll
      for (int j = 0; j < 2; j++) {
        unsigned short t8[8];
#pragma unroll
        for (int i = 0; i < 4; i++) {
          t8[i] = f2b(a0[j][i] + p0[j][i]);
          t8[4 + i] = f2b(a1[j][i] + p1[j][i]);
        }
        *(uint4*)&As[cur ^ 1][lOff[j] + lane * 8] = *(uint4*)t8;
      }
    }
    __syncthreads();
  }

#pragma unroll
  for (int i = 0; i < 2; i++) {
    float s1[4] = {0.f, 0.f, 0.f, 0.f};
    float s2[4] = {0.f, 0.f, 0.f, 0.f};
    const int rbase = m0 + wm * 32 + i * 16 + quad * 4;
#pragma unroll
    for (int j = 0; j < 2; j++) {
      const int c = n0 + wn * 32 + j * 16 + l16;
#pragma unroll
      for (int r = 0; r < 4; r++) {
        const int row = rbase + r;
        float v = acc[i][j][r] + rowsum[row] * bp[c];
        out[(long)row * ldc + c] = v;
        s1[r] += v;
        s2[r] += v * v;
      }
    }
#pragma unroll
    for (int r = 0; r < 4; r++) {
      float a = s1[r], b = s2[r];
      a += __shfl_xor(a, 1, 64); b += __shfl_xor(b, 1, 64);
      a += __shfl_xor(a, 2, 64); b += __shfl_xor(b, 2, 64);
      a += __shfl_xor(a, 4, 64); b += __shfl_xor(b, 4, 64);
      a += __shfl_xor(a, 8, 64); b += __shfl_xor(b, 8, 64);
      if (l16 == 0) {
        atomicAdd(rstat + (rbase + r) * 2, a);
        atomicAdd(rstat + (rbase + r) * 2 + 1, b);
      }
    }
  }
}

// ---------------- unified gates/cand GEMM, K-split x2, fused A-staging ------
// blockIdx.z = kc. amode (per slice): 0 = bf16 A via g2l16 (Abf, lda)
//   1 = on-the-fly LN: A[row][k] = (routed[row][k]-mean)*rstd*g_in[k]+be_in[k]
//   2 = on-the-fly r*psn: A[row][k] = sigmoid(gp0+gp1+br[k]) * psn[row][k]
// out f32 partials at [kc*sCk + row*ldc + c].
__global__ __launch_bounds__(256) void k_gemm2(
    const unsigned short* __restrict__ Abf, int lda,
    const float* __restrict__ routed, const float* __restrict__ rstat,
    const float* __restrict__ g_in, const float* __restrict__ be_in,
    const float* __restrict__ gparts, const float* __restrict__ br,
    const unsigned short* __restrict__ psn,
    const unsigned short* __restrict__ Bt, int ldb,
    int K, long sCk, int amode0, int amode1,
    float* __restrict__ out, int ldc) {
  __shared__ unsigned short As[2][64 * 64];
  __shared__ unsigned short Bs[2][64 * 64];
  const int tid = threadIdx.x;
  const int wave = tid >> 6, lane = tid & 63;
  const int kc = blockIdx.z;
  const int amode = kc == 0 ? amode0 : amode1;
  const long koff = (long)kc * K;
  const int flat = blockIdx.x + blockIdx.y * gridDim.x;
  const int q = (gridDim.x * gridDim.y) >> 3;
  const int swz = (flat & 7) * q + (flat >> 3);
  const int m0 = (swz % gridDim.x) * 64;
  const int n0 = (swz / gridDim.x) * 64;
  const int wm = wave & 1, wn = wave >> 1;
  const int l16 = lane & 15, quad = lane >> 4;
  const int srow8 = lane >> 3;
  const int c8 = ((lane & 7) ^ srow8) * 8;

  int arow[2];
  const unsigned short* gA[2];
  const unsigned short* gB[2];
  int lOff[2];
  float mean_[2], rstd_[2];
#pragma unroll
  for (int j = 0; j < 2; j++) {
    const int rb = wave * 16 + j * 8;
    arow[j] = m0 + rb + srow8;
    gA[j] = Abf ? Abf + (long)arow[j] * lda + c8 : nullptr;
    gB[j] = Bt + (long)(n0 + rb + srow8) * ldb + c8 + koff;
    lOff[j] = rb * 64;
    if (amode == 1) {
      const float s1 = rstat[arow[j] * 2];
      const float s2 = rstat[arow[j] * 2 + 1];
      const float mean = s1 * (1.0f / 1024.0f);
      const float var = s2 * (1.0f / 1024.0f) - mean * mean;
      mean_[j] = mean;
      rstd_[j] = rsqrtf(var + LN_EPS);
    }
  }
  int offA[2][2], offB[2][2];
#pragma unroll
  for (int ks = 0; ks < 2; ks++)
#pragma unroll
    for (int i = 0; i < 2; i++) {
      int r = wm * 32 + i * 16 + l16;
      offA[ks][i] = r * 64 + (((ks * 4 + quad) ^ (r & 7)) * 8);
      r = wn * 32 + i * 16 + l16;
      offB[ks][i] = r * 64 + (((ks * 4 + quad) ^ (r & 7)) * 8);
    }

  floatx4 acc[2][2] = {};

  // prologue: B async; A per mode directly into buf 0
#pragma unroll
  for (int j = 0; j < 2; j++) g2l16(gB[j], &Bs[0][lOff[j]]);
  if (amode == 0) {
#pragma unroll
    for (int j = 0; j < 2; j++) g2l16(gA[j], &As[0][lOff[j]]);
  } else if (amode == 1) {
#pragma unroll
    for (int j = 0; j < 2; j++) {
      floatx4 v0 = *(const floatx4*)(routed + (long)arow[j] * 1024 + c8);
      floatx4 v1 = *(const floatx4*)(routed + (long)arow[j] * 1024 + c8 + 4);
      floatx4 gg0 = *(const floatx4*)(g_in + c8);
      floatx4 gg1 = *(const floatx4*)(g_in + c8 + 4);
      floatx4 bb0 = *(const floatx4*)(be_in + c8);
      floatx4 bb1 = *(const floatx4*)(be_in + c8 + 4);
      unsigned short t8[8];
#pragma unroll
      for (int i = 0; i < 4; i++) {
        t8[i] = f2b((v0[i] - mean_[j]) * rstd_[j] * gg0[i] + bb0[i]);
        t8[4 + i] = f2b((v1[i] - mean_[j]) * rstd_[j] * gg1[i] + bb1[i]);
      }
      *(uint4*)&As[0][lOff[j] + lane * 8] = *(uint4*)t8;
    }
  } else {
#pragma unroll
    for (int j = 0; j < 2; j++) {
      const long gbase = (long)arow[j] * 2048 + 1024 + c8;
      floatx4 q0 = *(const floatx4*)(gparts + gbase);
      floatx4 q1 = *(const floatx4*)(gparts + gbase + 4);
      floatx4 q2 = *(const floatx4*)(gparts + 2097152 + gbase);
      floatx4 q3 = *(const floatx4*)(gparts + 2097152 + gbase + 4);
      floatx4 bb0 = *(const floatx4*)(br + c8);
      floatx4 bb1 = *(const floatx4*)(br + c8 + 4);
      uint4 pv = *(const uint4*)(psn + (long)arow[j] * 1024 + c8);
      const unsigned short* ph = (const unsigned short*)&pv;
      unsigned short t8[8];
#pragma unroll
      for (int i = 0; i < 4; i++) {
        t8[i] = f2b(sigm(q0[i] + q2[i] + bb0[i]) * b2f(ph[i]));
        t8[4 + i] = f2b(sigm(q1[i] + q3[i] + bb1[i]) * b2f(ph[4 + i]));
      }
      *(uint4*)&As[0][lOff[j] + lane * 8] = *(uint4*)t8;
    }
  }
  __syncthreads();

  const int nt = K >> 6;
  for (int t = 0; t < nt; t++) {
    const int cur = t & 1;
    const int kn = (t + 1) << 6;
    floatx4 rv0[2], rv1[2], q0[2], q1[2], q2[2], q3[2];
    uint4 pv[2];
    if (t + 1 < nt) {
#pragma unroll
      for (int j = 0; j < 2; j++) g2l16(gB[j] + kn, &Bs[cur ^ 1][lOff[j]]);
      if (amode == 0) {
#pragma unroll
        for (int j = 0; j < 2; j++) g2l16(gA[j] + kn, &As[cur ^ 1][lOff[j]]);
      } else if (amode == 1) {
#pragma unroll
        for (int j = 0; j < 2; j++) {
          rv0[j] = *(const floatx4*)(routed + (long)arow[j] * 1024 + kn + c8);
          rv1[j] = *(const floatx4*)(routed + (long)arow[j] * 1024 + kn + c8 + 4);
        }
      } else {
#pragma unroll
        for (int j = 0; j < 2; j++) {
          const long gbase = (long)arow[j] * 2048 + 1024 + kn + c8;
          q0[j] = *(const floatx4*)(gparts + gbase);
          q1[j] = *(const floatx4*)(gparts + gbase + 4);
          q2[j] = *(const floatx4*)(gparts + 2097152 + gbase);
          q3[j] = *(const floatx4*)(gparts + 2097152 + gbase + 4);
          pv[j] = *(const uint4*)(psn + (long)arow[j] * 1024 + kn + c8);
        }
      }
    }
#pragma unroll
    for (int ks = 0; ks < 2; ks++) {
      shortx8 af[2], bf[2];
#pragma unroll
      for (int i = 0; i < 2; i++) af[i] = *(const shortx8*)&As[cur][offA[ks][i]];
#pragma unroll
      for (int j = 0; j < 2; j++) bf[j] = *(const shortx8*)&Bs[cur][offB[ks][j]];
#pragma unroll
      for (int i = 0; i < 2; i++)
#pragma unroll
        for (int j = 0; j < 2; j++)
          acc[i][j] = __builtin_amdgcn_mfma_f32_16x16x32_bf16(af[i], bf[j], acc[i][j], 0, 0, 0);
    }
    if (t + 1 < nt) {
      if (amode == 1) {
#pragma unroll
        for (int j = 0; j < 2; j++) {
          floatx4 gg0 = *(const floatx4*)(g_in + kn + c8);
          floatx4 gg1 = *(const floatx4*)(g_in + kn + c8 + 4);
          floatx4 bb0 = *(const floatx4*)(be_in + kn + c8);
          floatx4 bb1 = *(const floatx4*)(be_in + kn + c8 + 4);
          unsigned short t8[8];
#pragma unroll
          for (int i = 0; i < 4; i++) {
            t8[i] = f2b((rv0[j][i] - mean_[j]) * rstd_[j] * gg0[i] + bb0[i]);
            t8[4 + i] = f2b((rv1[j][i] - mean_[j]) * rstd_[j] * gg1[i] + bb1[i]);
          }
          *(uint4*)&As[cur ^ 1][lOff[j] + lane * 8] = *(uint4*)t8;
        }
      } else if (amode == 2) {
#pragma unroll
        for (int j = 0; j < 2; j++) {
          floatx4 bb0 = *(const floatx4*)(br + kn + c8);
          floatx4 bb1 = *(const floatx4*)(br + kn + c8 + 4);
          const unsigned short* ph = (const unsigned short*)&pv[j];
          unsigned short t8[8];
#pragma unroll
          for (int i = 0; i < 4; i++) {
            t8[i] = f2b(sigm(q0[j][i] + q2[j][i] + bb0[i]) * b2f(ph[i]));
            t8[4 + i] = f2b(sigm(q1[j][i] + q3[j][i] + bb1[i]) * b2f(ph[4 + i]));
          }
          *(uint4*)&As[cur ^ 1][lOff[j] + lane * 8] = *(uint4*)t8;
        }
      }
    }
    __syncthreads();
  }

#pragma unroll
  for (int i = 0; i < 2; i++)
#pragma unroll
    for (int j = 0; j < 2; j++) {
      const int rbase = m0 + wm * 32 + i * 16 + quad * 4;
      const int c = n0 + wn * 32 + j * 16 + l16;
#pragma unroll
      for (int r = 0; r < 4; r++)
        out[(long)kc * sCk + (long)(rbase + r) * ldc + c] = acc[i][j][r];
    }
}

// ---------------- final: u + cand epilogue + LayerNorm -> f32 output --------
// u = sigmoid(gp0[r][c]+gp1[r][c]+bu[c]); ns = (1-u)*prev + u*tanh(cp0+cp1+bn)
__global__ __launch_bounds__(256) void k_ln_out(
    const float* __restrict__ cparts,  // [2][1024][1024]
    const float* __restrict__ gparts,  // [2][1024][2048] (u = cols 0..1023)
    const float* __restrict__ bu, const float* __restrict__ prev,
    const float* __restrict__ bn,
    const float* __restrict__ g, const float* __restrict__ be,
    float* __restrict__ out) {
  __shared__ float scr[4];
  const long r = blockIdx.x;
  const int t = threadIdx.x;
  floatx4 p0 = *(const floatx4*)(cparts + r * 1024 + t * 4);
  floatx4 p1 = *(const floatx4*)(cparts + 1048576 + r * 1024 + t * 4);
  floatx4 u0 = *(const floatx4*)(gparts + r * 2048 + t * 4);
  floatx4 u1 = *(const floatx4*)(gparts + 2097152 + r * 2048 + t * 4);
  floatx4 ub = *(const floatx4*)(bu + t * 4);
  floatx4 pv = *(const floatx4*)(prev + r * 1024 + t * 4);
  floatx4 bv = *(const floatx4*)(bn + t * 4);
  floatx4 v;
#pragma unroll
  for (int i = 0; i < 4; i++) {
    const float uu = sigm(u0[i] + u1[i] + ub[i]);
    const float cand = tanhf(p0[i] + p1[i] + bv[i]);
    v[i] = (1.0f - uu) * pv[i] + uu * cand;
  }
  float s1 = v[0] + v[1] + v[2] + v[3];
  float s2 = v[0] * v[0] + v[1] * v[1] + v[2] * v[2] + v[3] * v[3];
  s1 = block_sum(s1, scr);
  s2 = block_sum(s2, scr);
  const float mean = s1 * (1.0f / 1024.0f);
  const float var = s2 * (1.0f / 1024.0f) - mean * mean;
  const float rstd = rsqrtf(var + LN_EPS);
  floatx4 o;
#pragma unroll
  for (int i = 0; i < 4; i++) {
    const int d = t * 4 + i;
    o[i] = (v[i] - mean) * rstd * g[d] + be[d];
  }
  *(floatx4*)(out + r * 1024 + t * 4) = o;
}

// ---------------------------------------------------------------------------
extern "C" void kernel_launch(void* const* d_in, const int* in_sizes, int n_in,
                              void* d_out, int out_size, void* d_ws, size_t ws_size,
                              hipStream_t stream) {
  (void)in_sizes; (void)n_in; (void)out_size; (void)ws_size;
  const float* prev  = (const float*)d_in[0];
  const float* toks  = (const float*)d_in[1];
  const float* Wp    = (const float*)d_in[2];
  const float* bp    = (const float*)d_in[3];
  const float* g_st  = (const float*)d_in[4];
  const float* be_st = (const float*)d_in[5];
  const float* g_in  = (const float*)d_in[6];
  const float* be_in = (const float*)d_in[7];
  const float* g_o   = (const float*)d_in[8];
  const float* be_o  = (const float*)d_in[9];
  const float* Wu    = (const float*)d_in[10];
  const float* bu    = (const float*)d_in[11];
  const float* Wr    = (const float*)d_in[12];
  const float* br    = (const float*)d_in[13];
  const float* Wn    = (const float*)d_in[14];
  const float* bn    = (const float*)d_in[15];
  float* out = (float*)d_out;

  // ---- workspace (~60 MB)
  char* ws = (char*)d_ws;
  unsigned short* Wtp   = (unsigned short*)ws; ws += 1572864;   // 1024x768 bf16
  unsigned short* pwb   = (unsigned short*)ws; ws += 1572864;   // 1024x768 bf16
  unsigned short* attnb = (unsigned short*)ws; ws += 4194304;   // 16x64x2048 bf16
  float*          rowsum= (float*)ws;          ws += 4096;      // 1024 f32
  float*          rstat = (float*)ws;          ws += 8192;      // 1024x2 f32
  float*          parts = (float*)ws;          ws += 6291456;   // 2x 1024x768 f32
  float*          routed= (float*)ws;          ws += 4194304;   // 1024x1024 f32
  unsigned short* psn   = (unsigned short*)ws; ws += 2097152;   // 1024x1024 bf16
  unsigned short* Wtur  = (unsigned short*)ws; ws += 8388608;   // 2048x2048 bf16
  unsigned short* Wtn   = (unsigned short*)ws; ws += 4194304;   // 1024x2048 bf16
  float*          gparts= (float*)ws;          ws += 16777216;  // 2x 1024x2048 f32
  float*          cparts= (float*)ws;          ws += 8388608;   // 2x 1024x1024 f32

  const dim3 blk(256);

  // 1. merged: pw GEMM (f32-direct) + 4 transposes + zero rowsum/rstat
  k_prep_pw<<<dim3(7104), blk, 0, stream>>>(prev, Wp, Wu, Wr, Wn,
                                            Wtur, Wtn, Wtp, pwb, rowsum, rstat);
  // 2. attnb = exp(pw @ tokens^T / 32) + fused rowsum atomics
  k_scores<<<dim3(1, 32, 16), blk, 0, stream>>>(
      pwb, 49152L, 768, toks, 768, 0.03125f,
      attnb, 2048, 131072L, rowsum);
  // 3. rw partials = w @ tokens(f32), K-split x2
  k_routed_mfma<<<dim3(2, 12, 16), blk, 0, stream>>>(attnb, toks, parts);
  // 4. merged: proj2 (+row stats) + prev-LN -> psn
  k_proj2_ln<<<dim3(1280), blk, 0, stream>>>(
      parts, 768, Wtp, 768, 768, bp, rowsum, routed, 1024, rstat,
      prev, g_st, be_st, psn);
  // 5. gates GEMM: kc0 A=psn (g2l16), kc1 A=LN(routed) on-the-fly
  k_gemm2<<<dim3(16, 32, 2), blk, 0, stream>>>(
      psn, 1024, routed, rstat, g_in, be_in, nullptr, nullptr, nullptr,
      Wtur, 2048, 1024, 2097152L, 0, 1, gparts, 2048);
  // 6. cand GEMM: kc0 A=r*psn on-the-fly, kc1 A=LN(routed) on-the-fly
  k_gemm2<<<dim3(16, 16, 2), blk, 0, stream>>>(
      nullptr, 0, routed, rstat, g_in, be_in, gparts, br, psn,
      Wtn, 2048, 1024, 1048576L, 2, 1, cparts, 1024);
  // 7. fused u + cand epilogue + final LN -> output
  k_ln_out<<<dim3(1024), blk, 0, stream>>>(cparts, gparts, bu, prev, bn,
                                           g_o, be_o, out);
}

// Round 9
// 299.505 us; speedup vs baseline: 1.1532x; 1.1532x over previous
//
#include <hip/hip_runtime.h>
#include <stdint.h>

typedef __attribute__((ext_vector_type(4))) float floatx4;
typedef __attribute__((ext_vector_type(8))) short shortx8;

#define LN_EPS 1e-5f

__device__ __forceinline__ unsigned short f2b(float f) {
  unsigned u = __builtin_bit_cast(unsigned, f);
  u = (u + 0x7FFFu + ((u >> 16) & 1u)) >> 16;
  return (unsigned short)u;
}
__device__ __forceinline__ float b2f(unsigned short h) {
  return __builtin_bit_cast(float, (unsigned)h << 16);
}

// async global->LDS 16B: lds dest is wave-uniform base; lane i lands at base + i*16
__device__ __forceinline__ void g2l16(const unsigned short* g, unsigned short* l) {
  __builtin_amdgcn_global_load_lds(
      (const __attribute__((address_space(1))) unsigned int*)g,
      (__attribute__((address_space(3))) unsigned int*)l, 16, 0, 0);
}

// ---------------- block reduction helpers (256 threads = 4 waves) -----------
__device__ __forceinline__ float wave_sum(float v) {
#pragma unroll
  for (int o = 32; o; o >>= 1) v += __shfl_down(v, o, 64);
  return v;
}
__device__ __forceinline__ float block_sum(float v, float* s) {
  v = wave_sum(v);
  __syncthreads();
  if ((threadIdx.x & 63) == 0) s[threadIdx.x >> 6] = v;
  __syncthreads();
  return s[0] + s[1] + s[2] + s[3];
}

// ---------------- merged: pw GEMM (blocks 0..191) + transposes + rowsum -----
__global__ __launch_bounds__(256) void k_prep_pw(
    const float* __restrict__ prev, const float* __restrict__ wp,
    const float* __restrict__ Wu, const float* __restrict__ Wr,
    const float* __restrict__ Wn,
    unsigned short* __restrict__ Wtur, unsigned short* __restrict__ Wtn,
    unsigned short* __restrict__ Wtp, unsigned short* __restrict__ pwb,
    float* __restrict__ rs) {
  __shared__ unsigned short As[2][64 * 64];
  __shared__ unsigned short Bs[2][64 * 64];
  const int bid = blockIdx.x;
  const int tid = threadIdx.x;
  if (bid < 192) {
    const int wave = tid >> 6, lane = tid & 63;
    const int swz = (bid & 7) * 24 + (bid >> 3);  // XCD-bijective over 192
    const int m0 = (swz % 16) * 64;
    const int n0 = (swz / 16) * 64;
    const int wm = wave & 1, wn = wave >> 1;
    const int l16 = lane & 15, quad = lane >> 4;
    const int srow8 = lane >> 3;
    const int c8 = ((lane & 7) ^ srow8) * 8;

    const float* gAf[2];
    const float* gBf[2];
    int lOff[2];
#pragma unroll
    for (int j = 0; j < 2; j++) {
      const int rb = wave * 16 + j * 8;
      gAf[j] = prev + (long)(m0 + rb + srow8) * 1024 + c8;
      gBf[j] = wp + (long)(n0 + rb + srow8) * 1024 + c8;
      lOff[j] = rb * 64;
    }
    int offA[2][2], offB[2][2];
#pragma unroll
    for (int ks = 0; ks < 2; ks++)
#pragma unroll
      for (int i = 0; i < 2; i++) {
        int r = wm * 32 + i * 16 + l16;
        offA[ks][i] = r * 64 + (((ks * 4 + quad) ^ (r & 7)) * 8);
        r = wn * 32 + i * 16 + l16;
        offB[ks][i] = r * 64 + (((ks * 4 + quad) ^ (r & 7)) * 8);
      }

    floatx4 acc[2][2] = {};

#pragma unroll
    for (int j = 0; j < 2; j++) {
      floatx4 a0 = *(const floatx4*)(gAf[j]);
      floatx4 a1 = *(const floatx4*)(gAf[j] + 4);
      floatx4 b0 = *(const floatx4*)(gBf[j]);
      floatx4 b1 = *(const floatx4*)(gBf[j] + 4);
      unsigned short ta[8], tb[8];
#pragma unroll
      for (int i = 0; i < 4; i++) {
        ta[i] = f2b(a0[i]); ta[4 + i] = f2b(a1[i]);
        tb[i] = f2b(b0[i]); tb[4 + i] = f2b(b1[i]);
      }
      *(uint4*)&As[0][lOff[j] + lane * 8] = *(uint4*)ta;
      *(uint4*)&Bs[0][lOff[j] + lane * 8] = *(uint4*)tb;
    }
    __syncthreads();

    const int nt = 16;
    for (int t = 0; t < nt; t++) {
      const int cur = t & 1;
      floatx4 a0[2], a1[2], b0[2], b1[2];
      if (t + 1 < nt) {
        const int kn = (t + 1) << 6;
#pragma unroll
        for (int j = 0; j < 2; j++) {
          a0[j] = *(const floatx4*)(gAf[j] + kn);
          a1[j] = *(const floatx4*)(gAf[j] + kn + 4);
          b0[j] = *(const floatx4*)(gBf[j] + kn);
          b1[j] = *(const floatx4*)(gBf[j] + kn + 4);
        }
      }
#pragma unroll
      for (int ks = 0; ks < 2; ks++) {
        shortx8 af[2], bf[2];
#pragma unroll
        for (int i = 0; i < 2; i++) af[i] = *(const shortx8*)&As[cur][offA[ks][i]];
#pragma unroll
        for (int j = 0; j < 2; j++) bf[j] = *(const shortx8*)&Bs[cur][offB[ks][j]];
#pragma unroll
        for (int i = 0; i < 2; i++)
#pragma unroll
          for (int j = 0; j < 2; j++)
            acc[i][j] = __builtin_amdgcn_mfma_f32_16x16x32_bf16(af[i], bf[j], acc[i][j], 0, 0, 0);
      }
      if (t + 1 < nt) {
#pragma unroll
        for (int j = 0; j < 2; j++) {
          unsigned short ta[8], tb[8];
#pragma unroll
          for (int i = 0; i < 4; i++) {
            ta[i] = f2b(a0[j][i]); ta[4 + i] = f2b(a1[j][i]);
            tb[i] = f2b(b0[j][i]); tb[4 + i] = f2b(b1[j][i]);
          }
          *(uint4*)&As[cur ^ 1][lOff[j] + lane * 8] = *(uint4*)ta;
          *(uint4*)&Bs[cur ^ 1][lOff[j] + lane * 8] = *(uint4*)tb;
        }
      }
      __syncthreads();
    }

#pragma unroll
    for (int i = 0; i < 2; i++)
#pragma unroll
      for (int j = 0; j < 2; j++) {
        const int rbase = m0 + wm * 32 + i * 16 + quad * 4;
        const int c = n0 + wn * 32 + j * 16 + l16;
#pragma unroll
        for (int r = 0; r < 4; r++)
          pwb[(long)(rbase + r) * 768 + c] = f2b(acc[i][j][r]);
      }
    return;
  }
  // ---- transpose part (aliases LDS)
  float(*tile)[33] = (float(*)[33]) & As[0][0];
  if (bid == 192) {
    floatx4 z = {0.f, 0.f, 0.f, 0.f};
    *(floatx4*)(rs + tid * 4) = z;
  }
  int t = bid - 192;
  const float* in;
  unsigned short* out;
  int K, kx, ny;
  if (t < 6144) {
    const int which = t >> 11;
    const int t2 = t & 2047;
    kx = t2 & 63;
    ny = t2 >> 6;
    K = 2048;
    in = which == 0 ? Wu : (which == 1 ? Wr : Wn);
    out = which == 0 ? Wtur : (which == 1 ? Wtur + 1024 * 2048 : Wtn);
  } else {
    const int t2 = t - 6144;
    kx = t2 % 24;
    ny = t2 / 24;
    K = 768;
    in = wp;
    out = Wtp;
  }
  const int N = 1024;
  const int k0 = kx * 32, n0 = ny * 32;
  const int tx = tid & 31, ty = tid >> 5;
#pragma unroll
  for (int i = 0; i < 32; i += 8)
    tile[ty + i][tx] = in[(long)(k0 + ty + i) * N + n0 + tx];
  __syncthreads();
#pragma unroll
  for (int i = 0; i < 32; i += 8)
    out[(long)(n0 + ty + i) * K + k0 + tx] = f2b(tile[tx][ty + i]);
}

// ---------------- 64x64 MFMA GEMM, BK=64, dbuf, XCD-swizzled, K-splittable --
// K = PER-SLICE depth; blockIdx.z = k-slice. out: f32 partials.
__global__ __launch_bounds__(256) void k_gemm64(
    const unsigned short* __restrict__ A, int lda,
    const unsigned short* __restrict__ Bt, int ldb,
    int K, long sCk,
    float* __restrict__ out, int ldc) {
  __shared__ unsigned short As[2][64 * 64];
  __shared__ unsigned short Bs[2][64 * 64];
  const int tid = threadIdx.x;
  const int wave = tid >> 6, lane = tid & 63;
  const int kc = blockIdx.z;
  const long koff = (long)kc * K;
  const int flat = blockIdx.x + blockIdx.y * gridDim.x;
  const int q = (gridDim.x * gridDim.y) >> 3;
  const int swz = (flat & 7) * q + (flat >> 3);
  const int m0 = (swz % gridDim.x) * 64;
  const int n0 = (swz / gridDim.x) * 64;
  const int wm = wave & 1, wn = wave >> 1;
  const int l16 = lane & 15, quad = lane >> 4;
  const int srow8 = lane >> 3;
  const int c8 = ((lane & 7) ^ srow8) * 8;

  const unsigned short* gA[2];
  const unsigned short* gB[2];
  int lOff[2];
#pragma unroll
  for (int j = 0; j < 2; j++) {
    const int rb = wave * 16 + j * 8;
    gA[j] = A + (long)(m0 + rb + srow8) * lda + c8 + koff;
    gB[j] = Bt + (long)(n0 + rb + srow8) * ldb + c8 + koff;
    lOff[j] = rb * 64;
  }
  int offA[2][2], offB[2][2];
#pragma unroll
  for (int ks = 0; ks < 2; ks++)
#pragma unroll
    for (int i = 0; i < 2; i++) {
      int r = wm * 32 + i * 16 + l16;
      offA[ks][i] = r * 64 + (((ks * 4 + quad) ^ (r & 7)) * 8);
      r = wn * 32 + i * 16 + l16;
      offB[ks][i] = r * 64 + (((ks * 4 + quad) ^ (r & 7)) * 8);
    }

  floatx4 acc[2][2] = {};

#pragma unroll
  for (int j = 0; j < 2; j++) {
    g2l16(gA[j], &As[0][lOff[j]]);
    g2l16(gB[j], &Bs[0][lOff[j]]);
  }
  __syncthreads();

  const int nt = K >> 6;
  for (int t = 0; t < nt; t++) {
    const int cur = t & 1;
    if (t + 1 < nt) {
      const int kn = (t + 1) << 6;
#pragma unroll
      for (int j = 0; j < 2; j++) {
        g2l16(gA[j] + kn, &As[cur ^ 1][lOff[j]]);
        g2l16(gB[j] + kn, &Bs[cur ^ 1][lOff[j]]);
      }
    }
#pragma unroll
    for (int ks = 0; ks < 2; ks++) {
      shortx8 af[2], bf[2];
#pragma unroll
      for (int i = 0; i < 2; i++) af[i] = *(const shortx8*)&As[cur][offA[ks][i]];
#pragma unroll
      for (int j = 0; j < 2; j++) bf[j] = *(const shortx8*)&Bs[cur][offB[ks][j]];
#pragma unroll
      for (int i = 0; i < 2; i++)
#pragma unroll
        for (int j = 0; j < 2; j++)
          acc[i][j] = __builtin_amdgcn_mfma_f32_16x16x32_bf16(af[i], bf[j], acc[i][j], 0, 0, 0);
    }
    __syncthreads();
  }

#pragma unroll
  for (int i = 0; i < 2; i++)
#pragma unroll
    for (int j = 0; j < 2; j++) {
      const int rbase = m0 + wm * 32 + i * 16 + quad * 4;
      const int c = n0 + wn * 32 + j * 16 + l16;
#pragma unroll
      for (int r = 0; r < 4; r++)
        out[(long)kc * sCk + (long)(rbase + r) * ldc + c] = acc[i][j][r];
    }
}

// ---------------- proj2 (blocks 0..255) + prev-LN (blocks 256..1279) --------
// proj2 A = sum of FOUR f32 parts slices (reg-cvt staged).
__global__ __launch_bounds__(256) void k_proj2_ln(
    const float* __restrict__ P0, int lda,
    const unsigned short* __restrict__ Bt, int ldb,
    int K,
    const float* __restrict__ bp, const float* __restrict__ rowsum,
    float* __restrict__ out, int ldc,
    const float* __restrict__ prev,
    const float* __restrict__ g_st, const float* __restrict__ be_st,
    unsigned short* __restrict__ conc) {
  __shared__ unsigned short As[2][64 * 64];
  __shared__ unsigned short Bs[2][64 * 64];
  const int tid = threadIdx.x;
  if (blockIdx.x >= 256) {
    // ---- prev-LN
    float* scr = (float*)&As[0][0];
    const long r = blockIdx.x - 256;
    floatx4 v = *(const floatx4*)(prev + r * 1024 + tid * 4);
    float s1 = v[0] + v[1] + v[2] + v[3];
    float s2 = v[0] * v[0] + v[1] * v[1] + v[2] * v[2] + v[3] * v[3];
    s1 = block_sum(s1, scr);
    s2 = block_sum(s2, scr);
    const float mean = s1 * (1.0f / 1024.0f);
    const float var = s2 * (1.0f / 1024.0f) - mean * mean;
    const float rstd = rsqrtf(var + LN_EPS);
    unsigned short t4[4];
#pragma unroll
    for (int i = 0; i < 4; i++) {
      const int d = tid * 4 + i;
      t4[i] = f2b((v[i] - mean) * rstd * g_st[d] + be_st[d]);
    }
    *(uint2*)(conc + r * 2048 + tid * 4) = *(uint2*)t4;
    return;
  }
  // ---- proj2
  const int wave = tid >> 6, lane = tid & 63;
  const int flat = blockIdx.x;
  const int swz = (flat & 7) * 32 + (flat >> 3);  // bijective over 256
  const int m0 = (swz % 16) * 64;
  const int n0 = (swz / 16) * 64;
  const int wm = wave & 1, wn = wave >> 1;
  const int l16 = lane & 15, quad = lane >> 4;
  const int srow8 = lane >> 3;
  const int c8 = ((lane & 7) ^ srow8) * 8;

  const float* gAf[2];
  const unsigned short* gB[2];
  int lOff[2];
#pragma unroll
  for (int j = 0; j < 2; j++) {
    const int rb = wave * 16 + j * 8;
    gAf[j] = P0 + (long)(m0 + rb + srow8) * lda + c8;
    gB[j] = Bt + (long)(n0 + rb + srow8) * ldb + c8;
    lOff[j] = rb * 64;
  }
  int offA[2][2], offB[2][2];
#pragma unroll
  for (int ks = 0; ks < 2; ks++)
#pragma unroll
    for (int i = 0; i < 2; i++) {
      int r = wm * 32 + i * 16 + l16;
      offA[ks][i] = r * 64 + (((ks * 4 + quad) ^ (r & 7)) * 8);
      r = wn * 32 + i * 16 + l16;
      offB[ks][i] = r * 64 + (((ks * 4 + quad) ^ (r & 7)) * 8);
    }

  floatx4 acc[2][2] = {};

#pragma unroll
  for (int j = 0; j < 2; j++) {
    g2l16(gB[j], &Bs[0][lOff[j]]);
    floatx4 s0 = *(const floatx4*)(gAf[j]);
    floatx4 s1 = *(const floatx4*)(gAf[j] + 4);
#pragma unroll
    for (int p = 1; p < 4; p++) {
      s0 += *(const floatx4*)(gAf[j] + p * 786432);
      s1 += *(const floatx4*)(gAf[j] + p * 786432 + 4);
    }
    unsigned short t8[8];
#pragma unroll
    for (int i = 0; i < 4; i++) { t8[i] = f2b(s0[i]); t8[4 + i] = f2b(s1[i]); }
    *(uint4*)&As[0][lOff[j] + lane * 8] = *(uint4*)t8;
  }
  __syncthreads();

  const int nt = K >> 6;
  for (int t = 0; t < nt; t++) {
    const int cur = t & 1;
    floatx4 v0[2][4], v1[2][4];
    if (t + 1 < nt) {
      const int kn = (t + 1) << 6;
#pragma unroll
      for (int j = 0; j < 2; j++) {
        g2l16(gB[j] + kn, &Bs[cur ^ 1][lOff[j]]);
#pragma unroll
        for (int p = 0; p < 4; p++) {
          v0[j][p] = *(const floatx4*)(gAf[j] + kn + p * 786432);
          v1[j][p] = *(const floatx4*)(gAf[j] + kn + p * 786432 + 4);
        }
      }
    }
#pragma unroll
    for (int ks = 0; ks < 2; ks++) {
      shortx8 af[2], bf[2];
#pragma unroll
      for (int i = 0; i < 2; i++) af[i] = *(const shortx8*)&As[cur][offA[ks][i]];
#pragma unroll
      for (int j = 0; j < 2; j++) bf[j] = *(const shortx8*)&Bs[cur][offB[ks][j]];
#pragma unroll
      for (int i = 0; i < 2; i++)
#pragma unroll
        for (int j = 0; j < 2; j++)
          acc[i][j] = __builtin_amdgcn_mfma_f32_16x16x32_bf16(af[i], bf[j], acc[i][j], 0, 0, 0);
    }
    if (t + 1 < nt) {
#pragma unroll
      for (int j = 0; j < 2; j++) {
        floatx4 s0 = v0[j][0] + v0[j][1] + v0[j][2] + v0[j][3];
        floatx4 s1 = v1[j][0] + v1[j][1] + v1[j][2] + v1[j][3];
        unsigned short t8[8];
#pragma unroll
        for (int i = 0; i < 4; i++) { t8[i] = f2b(s0[i]); t8[4 + i] = f2b(s1[i]); }
        *(uint4*)&As[cur ^ 1][lOff[j] + lane * 8] = *(uint4*)t8;
      }
    }
    __syncthreads();
  }

#pragma unroll
  for (int i = 0; i < 2; i++)
#pragma unroll
    for (int j = 0; j < 2; j++) {
      const int rbase = m0 + wm * 32 + i * 16 + quad * 4;
      const int c = n0 + wn * 32 + j * 16 + l16;
#pragma unroll
      for (int r = 0; r < 4; r++) {
        const int row = rbase + r;
        out[(long)row * ldc + c] = acc[i][j][r] + rowsum[row] * bp[c];
      }
    }
}

// ---------------- scores: A=pwb bf16 (g2l16), B=tokens f32 (reg-cvt) --------
__global__ __launch_bounds__(256) void k_scores(
    const unsigned short* __restrict__ A, long sAb, int lda,
    const float* __restrict__ toksf,
    int K, float scale,
    unsigned short* __restrict__ out2, int ldc, long sCb,
    float* __restrict__ rs) {
  __shared__ unsigned short As[2][64 * 64];
  __shared__ unsigned short Bs[2][64 * 64];
  const int tid = threadIdx.x;
  const int wave = tid >> 6, lane = tid & 63;
  const int b = blockIdx.z;
  const int m0 = 0, n0 = blockIdx.y * 64;
  const int wm = wave & 1, wn = wave >> 1;
  const int l16 = lane & 15, quad = lane >> 4;
  const int srow8 = lane >> 3;
  const int c8 = ((lane & 7) ^ srow8) * 8;
  const unsigned short* Ab = A + (long)b * sAb;

  const unsigned short* gA[2];
  const float* gBf[2];
  int lOff[2];
#pragma unroll
  for (int j = 0; j < 2; j++) {
    const int rb = wave * 16 + j * 8;
    gA[j] = Ab + (long)(m0 + rb + srow8) * lda + c8;
    gBf[j] = toksf + (long)b * 1572864 + (long)(n0 + rb + srow8) * 768 + c8;
    lOff[j] = rb * 64;
  }
  int offA[2][2], offB[2][2];
#pragma unroll
  for (int ks = 0; ks < 2; ks++)
#pragma unroll
    for (int i = 0; i < 2; i++) {
      int r = wm * 32 + i * 16 + l16;
      offA[ks][i] = r * 64 + (((ks * 4 + quad) ^ (r & 7)) * 8);
      r = wn * 32 + i * 16 + l16;
      offB[ks][i] = r * 64 + (((ks * 4 + quad) ^ (r & 7)) * 8);
    }

  floatx4 acc[2][2] = {};

#pragma unroll
  for (int j = 0; j < 2; j++) {
    g2l16(gA[j], &As[0][lOff[j]]);
    floatx4 v0 = *(const floatx4*)(gBf[j]);
    floatx4 v1 = *(const floatx4*)(gBf[j] + 4);
    unsigned short t8[8];
#pragma unroll
    for (int i = 0; i < 4; i++) { t8[i] = f2b(v0[i]); t8[4 + i] = f2b(v1[i]); }
    *(uint4*)&Bs[0][lOff[j] + lane * 8] = *(uint4*)t8;
  }
  __syncthreads();

  const int nt = K >> 6;
  for (int t = 0; t < nt; t++) {
    const int cur = t & 1;
    floatx4 w0[2], w1[2];
    if (t + 1 < nt) {
      const int kn = (t + 1) << 6;
#pragma unroll
      for (int j = 0; j < 2; j++) {
        g2l16(gA[j] + kn, &As[cur ^ 1][lOff[j]]);
        w0[j] = *(const floatx4*)(gBf[j] + kn);
        w1[j] = *(const floatx4*)(gBf[j] + kn + 4);
      }
    }
#pragma unroll
    for (int ks = 0; ks < 2; ks++) {
      shortx8 af[2], bf[2];
#pragma unroll
      for (int i = 0; i < 2; i++) af[i] = *(const shortx8*)&As[cur][offA[ks][i]];
#pragma unroll
      for (int j = 0; j < 2; j++) bf[j] = *(const shortx8*)&Bs[cur][offB[ks][j]];
#pragma unroll
      for (int i = 0; i < 2; i++)
#pragma unroll
        for (int j = 0; j < 2; j++)
          acc[i][j] = __builtin_amdgcn_mfma_f32_16x16x32_bf16(af[i], bf[j], acc[i][j], 0, 0, 0);
    }
    if (t + 1 < nt) {
#pragma unroll
      for (int j = 0; j < 2; j++) {
        unsigned short t8[8];
#pragma unroll
        for (int i = 0; i < 4; i++) { t8[i] = f2b(w0[j][i]); t8[4 + i] = f2b(w1[j][i]); }
        *(uint4*)&Bs[cur ^ 1][lOff[j] + lane * 8] = *(uint4*)t8;
      }
    }
    __syncthreads();
  }

#pragma unroll
  for (int i = 0; i < 2; i++) {
    float psum[4] = {0.f, 0.f, 0.f, 0.f};
#pragma unroll
    for (int j = 0; j < 2; j++) {
      const int rbase = m0 + wm * 32 + i * 16 + quad * 4;
      const int c = n0 + wn * 32 + j * 16 + l16;
#pragma unroll
      for (int r = 0; r < 4; r++) {
        const float e = expf(acc[i][j][r] * scale);
        out2[(long)b * sCb + (long)(rbase + r) * ldc + c] = f2b(e);
        psum[r] += e;
      }
    }
#pragma unroll
    for (int r = 0; r < 4; r++) {
      float s = psum[r];
      s += __shfl_xor(s, 1, 64);
      s += __shfl_xor(s, 2, 64);
      s += __shfl_xor(s, 4, 64);
      s += __shfl_xor(s, 8, 64);
      if (l16 == 0)
        atomicAdd(rs + (long)b * 64 + m0 + wm * 32 + i * 16 + quad * 4 + r, s);
    }
  }
}

// ---------------- rw = attnb(exp) @ tokens(f32) via MFMA, K-split x4 --------
__global__ __launch_bounds__(256) void k_routed_mfma(
    const unsigned short* __restrict__ attnb,
    const float* __restrict__ tokf,
    float* __restrict__ parts) {
  __shared__ unsigned short As[64 * 40];
  __shared__ unsigned short Bs[32 * 66];
  const int kc = blockIdx.x, nt = blockIdx.y, b = blockIdx.z;
  const int tid = threadIdx.x;
  const int wave = tid >> 6, lane = tid & 63;
  const int wm = wave & 1, wn = wave >> 1;
  const int l16 = lane & 15, quad = lane >> 4;
  const int n0 = nt * 64;
  const long abase = (long)b * 131072 + (long)kc * 512;
  const long tbase = ((long)b * 2048 + (long)kc * 512) * 768;
  const int srow = tid >> 2, skc = (tid & 3) * 8;
  const int bk = tid >> 3, bd = (tid & 7) * 8;

  floatx4 acc[2][2] = {};

  uint4 pa = *(const uint4*)(attnb + abase + (long)srow * 2048 + skc);
  floatx4 f0 = *(const floatx4*)(tokf + tbase + (long)bk * 768 + n0 + bd);
  floatx4 f1 = *(const floatx4*)(tokf + tbase + (long)bk * 768 + n0 + bd + 4);

  for (int k0 = 0; k0 < 512; k0 += 32) {
    *(uint4*)&As[srow * 40 + skc] = pa;
    {
      unsigned short t8[8];
#pragma unroll
      for (int i = 0; i < 4; i++) { t8[i] = f2b(f0[i]); t8[4 + i] = f2b(f1[i]); }
      unsigned short* dst = &Bs[bk * 66 + bd];
#pragma unroll
      for (int w2 = 0; w2 < 4; w2++) *(unsigned*)(dst + w2 * 2) = ((unsigned*)t8)[w2];
    }
    if (k0 + 32 < 512) {
      pa = *(const uint4*)(attnb + abase + (long)srow * 2048 + (k0 + 32) + skc);
      f0 = *(const floatx4*)(tokf + tbase + (long)(k0 + 32 + bk) * 768 + n0 + bd);
      f1 = *(const floatx4*)(tokf + tbase + (long)(k0 + 32 + bk) * 768 + n0 + bd + 4);
    }
    asm volatile("s_waitcnt lgkmcnt(0)" ::: "memory");
    __builtin_amdgcn_s_barrier();
    __builtin_amdgcn_sched_barrier(0);

    shortx8 a0 = *(const shortx8*)&As[(wm * 32 + 0  + l16) * 40 + quad * 8];
    shortx8 a1 = *(const shortx8*)&As[(wm * 32 + 16 + l16) * 40 + quad * 8];
    shortx8 b0, b1;
#pragma unroll
    for (int j = 0; j < 8; j++) {
      b0[j] = *(const short*)&Bs[(quad * 8 + j) * 66 + wn * 32 + l16];
      b1[j] = *(const short*)&Bs[(quad * 8 + j) * 66 + wn * 32 + 16 + l16];
    }
    acc[0][0] = __builtin_amdgcn_mfma_f32_16x16x32_bf16(a0, b0, acc[0][0], 0, 0, 0);
    acc[0][1] = __builtin_amdgcn_mfma_f32_16x16x32_bf16(a0, b1, acc[0][1], 0, 0, 0);
    acc[1][0] = __builtin_amdgcn_mfma_f32_16x16x32_bf16(a1, b0, acc[1][0], 0, 0, 0);
    acc[1][1] = __builtin_amdgcn_mfma_f32_16x16x32_bf16(a1, b1, acc[1][1], 0, 0, 0);
    __builtin_amdgcn_s_barrier();
  }

#pragma unroll
  for (int im = 0; im < 2; im++)
#pragma unroll
    for (int in_ = 0; in_ < 2; in_++) {
      const int rbase = wm * 32 + im * 16 + quad * 4;
      const int c = n0 + wn * 32 + in_ * 16 + l16;
#pragma unroll
      for (int r = 0; r < 4; r++)
        parts[(long)kc * 786432 + ((long)b * 64 + rbase + r) * 768 + c] =
            acc[im][in_][r];
    }
}

// ---------------- routed LayerNorm -> conc second half + candA second half --
__global__ __launch_bounds__(256) void k_ln_routed(
    const float* __restrict__ routed,
    const float* __restrict__ g_in, const float* __restrict__ be_in,
    unsigned short* __restrict__ conc, unsigned short* __restrict__ candA) {
  __shared__ float scr[4];
  const long r = blockIdx.x;
  const int t = threadIdx.x;
  floatx4 v = *(const floatx4*)(routed + r * 1024 + t * 4);
  float s1 = v[0] + v[1] + v[2] + v[3];
  float s2 = v[0] * v[0] + v[1] * v[1] + v[2] * v[2] + v[3] * v[3];
  s1 = block_sum(s1, scr);
  s2 = block_sum(s2, scr);
  const float mean = s1 * (1.0f / 1024.0f);
  const float var = s2 * (1.0f / 1024.0f) - mean * mean;
  const float rstd = rsqrtf(var + LN_EPS);
  unsigned short t4[4];
#pragma unroll
  for (int i = 0; i < 4; i++) {
    const int d = t * 4 + i;
    t4[i] = f2b((v[i] - mean) * rstd * g_in[d] + be_in[d]);
  }
  *(uint2*)(conc + r * 2048 + 1024 + t * 4) = *(uint2*)t4;
  *(uint2*)(candA + r * 2048 + 1024 + t * 4) = *(uint2*)t4;
}

// ---------------- gates epilogue: sigmoid(p0+p1+bias) -> ubuf / r*psn -------
__global__ __launch_bounds__(256) void k_gate_epi(
    const float* __restrict__ gparts,  // [2][1024][2048]
    const float* __restrict__ bu, const float* __restrict__ br,
    const unsigned short* __restrict__ conc,
    float* __restrict__ ubuf, unsigned short* __restrict__ candA) {
  const int row = blockIdx.x >> 1;
  const int half = blockIdx.x & 1;
  const int t = threadIdx.x;
  const long base = (long)row * 2048 + half * 1024 + t * 4;
  floatx4 p0 = *(const floatx4*)(gparts + base);
  floatx4 p1 = *(const floatx4*)(gparts + 2097152 + base);
  const float* bias = half ? br : bu;
  floatx4 bv = *(const floatx4*)(bias + t * 4);
  if (!half) {
    floatx4 o;
#pragma unroll
    for (int i = 0; i < 4; i++)
      o[i] = 1.0f / (1.0f + expf(-(p0[i] + p1[i] + bv[i])));
    *(floatx4*)(ubuf + (long)row * 1024 + t * 4) = o;
  } else {
    unsigned short t4[4];
#pragma unroll
    for (int i = 0; i < 4; i++) {
      float rr = 1.0f / (1.0f + expf(-(p0[i] + p1[i] + bv[i])));
      t4[i] = f2b(rr * b2f(conc[(long)row * 2048 + t * 4 + i]));
    }
    *(uint2*)(candA + (long)row * 2048 + t * 4) = *(uint2*)t4;
  }
}

// ---------------- final: cand-epilogue (4 parts) + LayerNorm -> f32 output --
__global__ __launch_bounds__(256) void k_ln_out(
    const float* __restrict__ cparts,  // [4][1024][1024]
    const float* __restrict__ ubuf, const float* __restrict__ prev,
    const float* __restrict__ bn,
    const float* __restrict__ g, const float* __restrict__ be,
    float* __restrict__ out) {
  __shared__ float scr[4];
  const long r = blockIdx.x;
  const int t = threadIdx.x;
  floatx4 p = *(const floatx4*)(cparts + r * 1024 + t * 4);
#pragma unroll
  for (int k = 1; k < 4; k++)
    p += *(const floatx4*)(cparts + (long)k * 1048576 + r * 1024 + t * 4);
  floatx4 uu = *(const floatx4*)(ubuf + r * 1024 + t * 4);
  floatx4 pv = *(const floatx4*)(prev + r * 1024 + t * 4);
  floatx4 bv = *(const floatx4*)(bn + t * 4);
  floatx4 v;
#pragma unroll
  for (int i = 0; i < 4; i++) {
    const float cand = tanhf(p[i] + bv[i]);
    v[i] = (1.0f - uu[i]) * pv[i] + uu[i] * cand;
  }
  float s1 = v[0] + v[1] + v[2] + v[3];
  float s2 = v[0] * v[0] + v[1] * v[1] + v[2] * v[2] + v[3] * v[3];
  s1 = block_sum(s1, scr);
  s2 = block_sum(s2, scr);
  const float mean = s1 * (1.0f / 1024.0f);
  const float var = s2 * (1.0f / 1024.0f) - mean * mean;
  const float rstd = rsqrtf(var + LN_EPS);
  floatx4 o;
#pragma unroll
  for (int i = 0; i < 4; i++) {
    const int d = t * 4 + i;
    o[i] = (v[i] - mean) * rstd * g[d] + be[d];
  }
  *(floatx4*)(out + r * 1024 + t * 4) = o;
}

// ---------------------------------------------------------------------------
extern "C" void kernel_launch(void* const* d_in, const int* in_sizes, int n_in,
                              void* d_out, int out_size, void* d_ws, size_t ws_size,
                              hipStream_t stream) {
  (void)in_sizes; (void)n_in; (void)out_size; (void)ws_size;
  const float* prev  = (const float*)d_in[0];
  const float* toks  = (const float*)d_in[1];
  const float* Wp    = (const float*)d_in[2];
  const float* bp    = (const float*)d_in[3];
  const float* g_st  = (const float*)d_in[4];
  const float* be_st = (const float*)d_in[5];
  const float* g_in  = (const float*)d_in[6];
  const float* be_in = (const float*)d_in[7];
  const float* g_o   = (const float*)d_in[8];
  const float* be_o  = (const float*)d_in[9];
  const float* Wu    = (const float*)d_in[10];
  const float* bu    = (const float*)d_in[11];
  const float* Wr    = (const float*)d_in[12];
  const float* br    = (const float*)d_in[13];
  const float* Wn    = (const float*)d_in[14];
  const float* bn    = (const float*)d_in[15];
  float* out = (float*)d_out;

  // ---- workspace (~85 MB)
  char* ws = (char*)d_ws;
  unsigned short* Wtp   = (unsigned short*)ws; ws += 1572864;   // 1024x768 bf16
  unsigned short* pwb   = (unsigned short*)ws; ws += 1572864;   // 1024x768 bf16
  unsigned short* attnb = (unsigned short*)ws; ws += 4194304;   // 16x64x2048 bf16
  float*          rowsum= (float*)ws;          ws += 4096;      // 1024 f32
  float*          parts = (float*)ws;          ws += 12582912;  // 4x 1024x768 f32
  float*          routed= (float*)ws;          ws += 4194304;   // 1024x1024 f32
  unsigned short* conc  = (unsigned short*)ws; ws += 4194304;   // 1024x2048 bf16
  unsigned short* candA = (unsigned short*)ws; ws += 4194304;   // 1024x2048 bf16
  float*          ubuf  = (float*)ws;          ws += 4194304;   // 1024x1024 f32
  unsigned short* Wtur  = (unsigned short*)ws; ws += 8388608;   // 2048x2048 bf16
  unsigned short* Wtn   = (unsigned short*)ws; ws += 4194304;   // 1024x2048 bf16
  float*          gparts= (float*)ws;          ws += 16777216;  // 2x 1024x2048 f32
  float*          cparts= (float*)ws;          ws += 16777216;  // 4x 1024x1024 f32

  const dim3 blk(256);

  // 1. merged: pw GEMM (f32-direct) + 4 transposes + rowsum zero
  k_prep_pw<<<dim3(7104), blk, 0, stream>>>(prev, Wp, Wu, Wr, Wn,
                                            Wtur, Wtn, Wtp, pwb, rowsum);
  // 2. attnb = exp(pw @ tokens^T / 32) + fused rowsum atomics, 512 blocks
  k_scores<<<dim3(1, 32, 16), blk, 0, stream>>>(
      pwb, 49152L, 768, toks, 768, 0.03125f,
      attnb, 2048, 131072L, rowsum);
  // 3. rw partials = w @ tokens(f32), K-split x4, 768 blocks
  k_routed_mfma<<<dim3(4, 12, 16), blk, 0, stream>>>(attnb, toks, parts);
  // 4. merged: proj2 (sums 4 parts) + prev-LN
  k_proj2_ln<<<dim3(1280), blk, 0, stream>>>(
      parts, 768, Wtp, 768, 768, bp, rowsum, routed, 1024,
      prev, g_st, be_st, conc);
  // 5. routed LN -> conc/candA second halves
  k_ln_routed<<<dim3(1024), blk, 0, stream>>>(routed, g_in, be_in, conc, candA);
  // 6. u|r gates GEMM, K-split x2 (f32 partials), 1024 blocks
  k_gemm64<<<dim3(16, 32, 2), blk, 0, stream>>>(
      conc, 2048, Wtur, 2048, 1024, 2097152L, gparts, 2048);
  // 7. gates epilogue: sigmoid + r*ps_n, 2048 blocks
  k_gate_epi<<<dim3(2048), blk, 0, stream>>>(gparts, bu, br, conc, ubuf, candA);
  // 8. cand GEMM, K-split x4 (f32 partials), 1024 blocks
  k_gemm64<<<dim3(16, 16, 4), blk, 0, stream>>>(
      candA, 2048, Wtn, 2048, 512, 1048576L, cparts, 1024);
  // 9. fused cand-epilogue + final LN -> output
  k_ln_out<<<dim3(1024), blk, 0, stream>>>(cparts, ubuf, prev, bn, g_o, be_o, out);
}